// Round 4
// baseline (512.827 us; speedup 1.0000x reference)
//
#include <hip/hip_runtime.h>
#include <cstdint>

#define NN 65536
#define MM 1024
#define CC 128
#define MDIM 256

typedef short short8 __attribute__((ext_vector_type(8)));
typedef float f32x4 __attribute__((ext_vector_type(4)));

__device__ __forceinline__ unsigned short f2bf(float f) {
  unsigned int u = __float_as_uint(f);
  unsigned int r = (u + 0x7fffu + ((u >> 16) & 1u)) >> 16;  // RNE
  return (unsigned short)r;
}
__device__ __forceinline__ float bf2f(unsigned int us) {
  return __uint_as_float(us << 16);
}

// ---------------------------------------------------------------------------
// weights_prep: W_map, W_att -> bf16; W_ih, W_hh -> bf16 hi/lo split.
// 2048 elems/block. Regions: Wmap 16 blk | Watt 8 | Wih 48 | Whh 96 = 168.
// ---------------------------------------------------------------------------
__global__ __launch_bounds__(256) void weights_prep(
    const float* __restrict__ Wmap, const float* __restrict__ Watt,
    const float* __restrict__ Wih, const float* __restrict__ Whh,
    unsigned short* __restrict__ Wmap_bf, unsigned short* __restrict__ Watt_bf,
    unsigned short* __restrict__ Wih_hi, unsigned short* __restrict__ Wih_lo,
    unsigned short* __restrict__ Whh_hi, unsigned short* __restrict__ Whh_lo) {
  int idx = blockIdx.x * 2048 + threadIdx.x * 8;
  if (idx < 49152) {
    const float* s;
    unsigned short* d;
    if (idx < 32768) { s = Wmap + idx; d = Wmap_bf + idx; }
    else             { s = Watt + idx - 32768; d = Watt_bf + idx - 32768; }
#pragma unroll
    for (int i = 0; i < 8; i += 4) {
      float4 v = *(const float4*)(s + i);
      ushort4 u;
      u.x = f2bf(v.x); u.y = f2bf(v.y); u.z = f2bf(v.z); u.w = f2bf(v.w);
      *(ushort4*)(d + i) = u;
    }
  } else {
    const float* s;
    unsigned short *dh, *dl;
    if (idx < 147456) { int o = idx - 49152;  s = Wih + o; dh = Wih_hi + o; dl = Wih_lo + o; }
    else              { int o = idx - 147456; s = Whh + o; dh = Whh_hi + o; dl = Whh_lo + o; }
#pragma unroll
    for (int i = 0; i < 8; i += 4) {
      float4 v = *(const float4*)(s + i);
      ushort4 uh, ul;
      uh.x = f2bf(v.x); ul.x = f2bf(v.x - bf2f(uh.x));
      uh.y = f2bf(v.y); ul.y = f2bf(v.y - bf2f(uh.y));
      uh.z = f2bf(v.z); ul.z = f2bf(v.z - bf2f(uh.z));
      uh.w = f2bf(v.w); ul.w = f2bf(v.w - bf2f(uh.w));
      *(ushort4*)(dh + i) = uh;
      *(ushort4*)(dl + i) = ul;
    }
  }
}

// ---------------------------------------------------------------------------
// node_mol: one block per molecule m (rows m + j*1024, j=0..63).
//  1. stage nf fp32 -> bf16 LDS (read nf once), fused a_node dot
//  2. map-pool MFMA -> mol0 (fp32 + hi/lo), col sums to LDS mp[]
//  3. h MFMA -> h_bf global (for iter-2 attend), biased acc kept in regs
//  4. iter-1 attend fused: molp dot + softmax + context from reg-resident h
// ---------------------------------------------------------------------------
__global__ __launch_bounds__(256) void node_mol(
    const float* __restrict__ nf, const float* __restrict__ W_align,
    const float* __restrict__ b_align,
    const unsigned short* __restrict__ Wmap_bf, const float* __restrict__ bmap,
    const unsigned short* __restrict__ Watt_bf, const float* __restrict__ batt,
    float* __restrict__ a_node, unsigned short* __restrict__ h_bf,
    float* __restrict__ mol0, unsigned short* __restrict__ mol_hi,
    unsigned short* __restrict__ mol_lo,
    unsigned short* __restrict__ ctx_hi, unsigned short* __restrict__ ctx_lo) {
  __shared__ __align__(16) unsigned short tile[64][136];  // +8 pad: 2-way max
  __shared__ float sc[64];
  __shared__ float mp[256];
  const int m = blockIdx.x;
  const int t = threadIdx.x;
  const int w = t >> 6, l = t & 63;
  const int lane16 = l & 15, quad = l >> 4;
  const float* w1 = W_align;
  const float* w2 = W_align + MDIM;

  // --- stage + a_node (4 threads per row, 64B-coalesced chunks) ---
  {
    const int j = t >> 2;
    const int node = m + j * MM;
    const float* src = nf + (size_t)node * CC;
    float part = 0.0f;
#pragma unroll
    for (int i = 0; i < 8; ++i) {
      const int c = ((t & 3) + i * 4) * 4;
      float4 v = *(const float4*)(src + c);
      float4 wv = *(const float4*)(w2 + c);
      part += v.x * wv.x + v.y * wv.y + v.z * wv.z + v.w * wv.w;
      ushort4 u;
      u.x = f2bf(v.x); u.y = f2bf(v.y); u.z = f2bf(v.z); u.w = f2bf(v.w);
      *(ushort4*)&tile[j][c] = u;
    }
    part += __shfl_xor(part, 1);
    part += __shfl_xor(part, 2);
    if ((t & 3) == 0) {
      float an = part + b_align[0];
      a_node[node] = an;
      sc[j] = an;
    }
  }
  __syncthreads();

  // --- map-pool: wave w covers cols [64w, 64w+64) ---
  {
    f32x4 acc[4][4];
#pragma unroll
    for (int a = 0; a < 4; ++a)
#pragma unroll
      for (int b = 0; b < 4; ++b) acc[a][b] = (f32x4){0.f, 0.f, 0.f, 0.f};
#pragma unroll
    for (int ks = 0; ks < 4; ++ks) {
      const int k0 = ks * 32 + quad * 8;
      short8 af[4], bfr[4];
#pragma unroll
      for (int mt = 0; mt < 4; ++mt)
        af[mt] = *(const short8*)&tile[mt * 16 + lane16][k0];
#pragma unroll
      for (int nt = 0; nt < 4; ++nt)
        bfr[nt] = *(const short8*)(Wmap_bf + (size_t)(w * 64 + nt * 16 + lane16) * CC + k0);
#pragma unroll
      for (int mt = 0; mt < 4; ++mt)
#pragma unroll
        for (int nt = 0; nt < 4; ++nt)
          acc[mt][nt] = __builtin_amdgcn_mfma_f32_16x16x32_bf16(
              af[mt], bfr[nt], acc[mt][nt], 0, 0, 0);
    }
#pragma unroll
    for (int nt = 0; nt < 4; ++nt) {
      const int col = w * 64 + nt * 16 + lane16;
      const float b = bmap[col];
      float s = 0.0f;
#pragma unroll
      for (int mt = 0; mt < 4; ++mt)
#pragma unroll
        for (int r = 0; r < 4; ++r) {
          float v = acc[mt][nt][r] + b;
          s += (v > 0.0f) ? v : 0.01f * v;
        }
      s += __shfl_xor(s, 16);
      s += __shfl_xor(s, 32);
      if (quad == 0) {
        mol0[(size_t)m * MDIM + col] = s;
        unsigned short hi = f2bf(s);
        mol_hi[(size_t)m * MDIM + col] = hi;
        mol_lo[(size_t)m * MDIM + col] = f2bf(s - bf2f(hi));
        mp[col] = s;
      }
    }
  }

  // --- h: wave w covers cols [32w, 32w+32); keep biased fp32 acc ---
  f32x4 hacc[4][2];
#pragma unroll
  for (int a = 0; a < 4; ++a) {
    hacc[a][0] = (f32x4){0.f, 0.f, 0.f, 0.f};
    hacc[a][1] = (f32x4){0.f, 0.f, 0.f, 0.f};
  }
#pragma unroll
  for (int ks = 0; ks < 4; ++ks) {
    const int k0 = ks * 32 + quad * 8;
    short8 af[4], bfr[2];
#pragma unroll
    for (int mt = 0; mt < 4; ++mt)
      af[mt] = *(const short8*)&tile[mt * 16 + lane16][k0];
#pragma unroll
    for (int nt = 0; nt < 2; ++nt)
      bfr[nt] = *(const short8*)(Watt_bf + (size_t)(w * 32 + nt * 16 + lane16) * CC + k0);
#pragma unroll
    for (int mt = 0; mt < 4; ++mt)
#pragma unroll
      for (int nt = 0; nt < 2; ++nt)
        hacc[mt][nt] = __builtin_amdgcn_mfma_f32_16x16x32_bf16(
            af[mt], bfr[nt], hacc[mt][nt], 0, 0, 0);
  }
#pragma unroll
  for (int nt = 0; nt < 2; ++nt) {
    const int col = w * 32 + nt * 16 + lane16;
    const float b = batt[col];
#pragma unroll
    for (int mt = 0; mt < 4; ++mt)
#pragma unroll
      for (int r = 0; r < 4; ++r) {
        const int j = mt * 16 + quad * 4 + r;
        float hv = hacc[mt][nt][r] + b;
        hacc[mt][nt][r] = hv;
        h_bf[(size_t)(m + j * MM) * CC + col] = f2bf(hv);
      }
  }
  __syncthreads();  // mp[] complete

  // --- iter-1 attend fused ---
  float4 mpv = *(const float4*)&mp[l * 4];
  float4 w1v = *(const float4*)(w1 + l * 4);
  float molp = mpv.x * w1v.x + mpv.y * w1v.y + mpv.z * w1v.z + mpv.w * w1v.w;
#pragma unroll
  for (int off = 32; off; off >>= 1) molp += __shfl_xor(molp, off);
  float a = sc[l] + molp;
  a = a > 0.0f ? a : 0.01f * a;
  float mx = a;
#pragma unroll
  for (int off = 32; off; off >>= 1) mx = fmaxf(mx, __shfl_xor(mx, off));
  float e = __expf(a - mx);
  float s = e;
#pragma unroll
  for (int off = 32; off; off >>= 1) s += __shfl_xor(s, off);
  const float wl = e / s;  // softmax weight for j = l (this wave's copy)

#pragma unroll
  for (int nt = 0; nt < 2; ++nt) {
    const int col = w * 32 + nt * 16 + lane16;
    float csum = 0.0f;
#pragma unroll
    for (int mt = 0; mt < 4; ++mt)
#pragma unroll
      for (int r = 0; r < 4; ++r) {
        const int j = mt * 16 + quad * 4 + r;
        csum = fmaf(__shfl(wl, j), hacc[mt][nt][r], csum);
      }
    csum += __shfl_xor(csum, 16);
    csum += __shfl_xor(csum, 32);
    if (quad == 0) {
      float o = csum > 0.0f ? csum : (__expf(csum) - 1.0f);  // ELU
      unsigned short hi = f2bf(o);
      ctx_hi[(size_t)m * CC + col] = hi;
      ctx_lo[(size_t)m * CC + col] = f2bf(o - bf2f(hi));
    }
  }
}

// ---------------------------------------------------------------------------
// attend (iter-2): per-molecule mol.w1 + leaky + softmax + context from bf16 h
// + ELU; ctx out as hi/lo split. 1 wave/molecule.
// ---------------------------------------------------------------------------
__global__ __launch_bounds__(64) void attend(
    const unsigned short* __restrict__ h_bf, const float* __restrict__ a_node,
    const float* __restrict__ mol, const float* __restrict__ w1,
    unsigned short* __restrict__ ctx_hi, unsigned short* __restrict__ ctx_lo) {
  const int m = blockIdx.x;
  const int l = threadIdx.x;
  float4 mv = *(const float4*)(mol + (size_t)m * MDIM + l * 4);
  float4 wv = *(const float4*)(w1 + l * 4);
  float molp = mv.x * wv.x + mv.y * wv.y + mv.z * wv.z + mv.w * wv.w;
#pragma unroll
  for (int off = 32; off; off >>= 1) molp += __shfl_xor(molp, off);
  float a = a_node[m + l * MM] + molp;
  a = a > 0.0f ? a : 0.01f * a;
  float mx = a;
#pragma unroll
  for (int off = 32; off; off >>= 1) mx = fmaxf(mx, __shfl_xor(mx, off));
  float e = __expf(a - mx);
  float s = e;
#pragma unroll
  for (int off = 32; off; off >>= 1) s += __shfl_xor(s, off);
  const float wl = e / s;
  float a0 = 0.f, a1 = 0.f;
#pragma unroll 4
  for (int j = 0; j < 64; ++j) {
    float wj = __shfl(wl, j);
    unsigned int u = *(const unsigned int*)(h_bf + (size_t)(m + j * MM) * CC + 2 * l);
    a0 = fmaf(wj, bf2f(u & 0xffffu), a0);
    a1 = fmaf(wj, bf2f(u >> 16), a1);
  }
  float o0 = a0 > 0.f ? a0 : (__expf(a0) - 1.0f);
  float o1 = a1 > 0.f ? a1 : (__expf(a1) - 1.0f);
  unsigned short h0 = f2bf(o0), h1 = f2bf(o1);
  unsigned short l0 = f2bf(o0 - bf2f(h0)), l1 = f2bf(o1 - bf2f(h1));
  *(unsigned int*)(ctx_hi + (size_t)m * CC + 2 * l) = (unsigned int)h0 | ((unsigned int)h1 << 16);
  *(unsigned int*)(ctx_lo + (size_t)m * CC + 2 * l) = (unsigned int)l0 | ((unsigned int)l1 << 16);
}

// ---------------------------------------------------------------------------
// gru_fused: gi = ctx@Wih^T, gh = mol@Whh^T (both hi/lo split, 3-term MFMA),
// gate + relu. grid (8 dtiles x 16 mtiles), block 256, no LDS.
// ---------------------------------------------------------------------------
__global__ __launch_bounds__(256) void gru_fused(
    const unsigned short* __restrict__ ctxh, const unsigned short* __restrict__ ctxl,
    const float* __restrict__ molprev,
    const unsigned short* __restrict__ molh, const unsigned short* __restrict__ moll,
    const unsigned short* __restrict__ Wih_hi, const unsigned short* __restrict__ Wih_lo,
    const unsigned short* __restrict__ Whh_hi, const unsigned short* __restrict__ Whh_lo,
    const float* __restrict__ b_ih, const float* __restrict__ b_hh,
    float* __restrict__ out_f32, unsigned short* __restrict__ out_hi,
    unsigned short* __restrict__ out_lo) {
  const int t = threadIdx.x;
  const int w = t >> 6, l = t & 63;
  const int lane16 = l & 15, quad = l >> 4;
  const int d0 = blockIdx.x * 32;
  const int m0 = blockIdx.y * 64;
  const int rw = m0 + w * 16 + lane16;

  f32x4 acc_i[6], acc_h[6];
#pragma unroll
  for (int i = 0; i < 6; ++i) {
    acc_i[i] = (f32x4){0.f, 0.f, 0.f, 0.f};
    acc_h[i] = (f32x4){0.f, 0.f, 0.f, 0.f};
  }

#pragma unroll
  for (int ks = 0; ks < 4; ++ks) {
    const int k0 = ks * 32 + quad * 8;
    short8 ah = *(const short8*)(ctxh + (size_t)rw * CC + k0);
    short8 al = *(const short8*)(ctxl + (size_t)rw * CC + k0);
#pragma unroll
    for (int nt = 0; nt < 6; ++nt) {
      const int brow = (nt >> 1) * 256 + d0 + (nt & 1) * 16 + lane16;
      short8 bh = *(const short8*)(Wih_hi + (size_t)brow * CC + k0);
      short8 bl = *(const short8*)(Wih_lo + (size_t)brow * CC + k0);
      acc_i[nt] = __builtin_amdgcn_mfma_f32_16x16x32_bf16(ah, bh, acc_i[nt], 0, 0, 0);
      acc_i[nt] = __builtin_amdgcn_mfma_f32_16x16x32_bf16(ah, bl, acc_i[nt], 0, 0, 0);
      acc_i[nt] = __builtin_amdgcn_mfma_f32_16x16x32_bf16(al, bh, acc_i[nt], 0, 0, 0);
    }
  }
#pragma unroll
  for (int ks = 0; ks < 8; ++ks) {
    const int k0 = ks * 32 + quad * 8;
    short8 ah = *(const short8*)(molh + (size_t)rw * MDIM + k0);
    short8 al = *(const short8*)(moll + (size_t)rw * MDIM + k0);
#pragma unroll
    for (int nt = 0; nt < 6; ++nt) {
      const int brow = (nt >> 1) * 256 + d0 + (nt & 1) * 16 + lane16;
      short8 bh = *(const short8*)(Whh_hi + (size_t)brow * MDIM + k0);
      short8 bl = *(const short8*)(Whh_lo + (size_t)brow * MDIM + k0);
      acc_h[nt] = __builtin_amdgcn_mfma_f32_16x16x32_bf16(ah, bh, acc_h[nt], 0, 0, 0);
      acc_h[nt] = __builtin_amdgcn_mfma_f32_16x16x32_bf16(ah, bl, acc_h[nt], 0, 0, 0);
      acc_h[nt] = __builtin_amdgcn_mfma_f32_16x16x32_bf16(al, bh, acc_h[nt], 0, 0, 0);
    }
  }

#pragma unroll
  for (int nt0 = 0; nt0 < 2; ++nt0) {
    const int d = d0 + nt0 * 16 + lane16;
    const float bir = b_ih[d],       bhr = b_hh[d];
    const float biz = b_ih[d + 256], bhz = b_hh[d + 256];
    const float bin = b_ih[d + 512], bhn = b_hh[d + 512];
#pragma unroll
    for (int r = 0; r < 4; ++r) {
      const int row = m0 + w * 16 + quad * 4 + r;
      float ir = acc_i[nt0][r] + bir,     hr = acc_h[nt0][r] + bhr;
      float iz = acc_i[nt0 + 2][r] + biz, hz = acc_h[nt0 + 2][r] + bhz;
      float in = acc_i[nt0 + 4][r] + bin, hn = acc_h[nt0 + 4][r] + bhn;
      float rg = 1.0f / (1.0f + __expf(-(ir + hr)));
      float z  = 1.0f / (1.0f + __expf(-(iz + hz)));
      float n  = tanhf(in + rg * hn);
      float hp = molprev[(size_t)row * MDIM + d];
      float v = (1.0f - z) * n + z * hp;
      v = v > 0.0f ? v : 0.0f;
      out_f32[(size_t)row * MDIM + d] = v;
      if (out_hi) {
        unsigned short hi = f2bf(v);
        out_hi[(size_t)row * MDIM + d] = hi;
        out_lo[(size_t)row * MDIM + d] = f2bf(v - bf2f(hi));
      }
    }
  }
}

// ---------------------------------------------------------------------------
extern "C" void kernel_launch(void* const* d_in, const int* in_sizes, int n_in,
                              void* d_out, int out_size, void* d_ws, size_t ws_size,
                              hipStream_t stream) {
  const float* nf      = (const float*)d_in[0];
  const float* W_map   = (const float*)d_in[3];
  const float* b_map   = (const float*)d_in[4];
  const float* W_att   = (const float*)d_in[5];
  const float* b_att   = (const float*)d_in[6];
  const float* W_align = (const float*)d_in[7];
  const float* b_align = (const float*)d_in[8];
  const float* W_ih    = (const float*)d_in[9];
  const float* b_ih    = (const float*)d_in[10];
  const float* W_hh    = (const float*)d_in[11];
  const float* b_hh    = (const float*)d_in[12];
  float* outp = (float*)d_out;

  float* ws = (float*)d_ws;
  unsigned short* h_bf    = (unsigned short*)ws; ws += (size_t)NN * CC / 2;
  unsigned short* Wmap_bf = (unsigned short*)ws; ws += MDIM * CC / 2;
  unsigned short* Watt_bf = (unsigned short*)ws; ws += CC * CC / 2;
  unsigned short* Wih_hi  = (unsigned short*)ws; ws += 768 * CC / 2;
  unsigned short* Wih_lo  = (unsigned short*)ws; ws += 768 * CC / 2;
  unsigned short* Whh_hi  = (unsigned short*)ws; ws += 768 * MDIM / 2;
  unsigned short* Whh_lo  = (unsigned short*)ws; ws += 768 * MDIM / 2;
  unsigned short* ctx_hi  = (unsigned short*)ws; ws += (size_t)MM * CC / 2;
  unsigned short* ctx_lo  = (unsigned short*)ws; ws += (size_t)MM * CC / 2;
  unsigned short* molA_hi = (unsigned short*)ws; ws += (size_t)MM * MDIM / 2;
  unsigned short* molA_lo = (unsigned short*)ws; ws += (size_t)MM * MDIM / 2;
  unsigned short* molB_hi = (unsigned short*)ws; ws += (size_t)MM * MDIM / 2;
  unsigned short* molB_lo = (unsigned short*)ws; ws += (size_t)MM * MDIM / 2;
  float* a_node = ws; ws += NN;
  float* mol_a  = ws; ws += (size_t)MM * MDIM;
  float* mol_b  = ws; ws += (size_t)MM * MDIM;

  weights_prep<<<dim3(168), 256, 0, stream>>>(W_map, W_att, W_ih, W_hh,
                                              Wmap_bf, Watt_bf,
                                              Wih_hi, Wih_lo, Whh_hi, Whh_lo);
  node_mol<<<dim3(1024), 256, 0, stream>>>(nf, W_align, b_align,
                                           Wmap_bf, b_map, Watt_bf, b_att,
                                           a_node, h_bf, mol_a, molA_hi, molA_lo,
                                           ctx_hi, ctx_lo);
  gru_fused<<<dim3(8, 16), 256, 0, stream>>>(ctx_hi, ctx_lo, mol_a, molA_hi, molA_lo,
                                             Wih_hi, Wih_lo, Whh_hi, Whh_lo,
                                             b_ih, b_hh, mol_b, molB_hi, molB_lo);
  attend<<<dim3(1024), 64, 0, stream>>>(h_bf, a_node, mol_b, W_align, ctx_hi, ctx_lo);
  gru_fused<<<dim3(8, 16), 256, 0, stream>>>(ctx_hi, ctx_lo, mol_b, molB_hi, molB_lo,
                                             Wih_hi, Wih_lo, Whh_hi, Whh_lo,
                                             b_ih, b_hh, outp,
                                             (unsigned short*)nullptr,
                                             (unsigned short*)nullptr);
}